// Round 7
// baseline (657.341 us; speedup 1.0000x reference)
//
#include <hip/hip_runtime.h>
#include <hip/hip_cooperative_groups.h>
#include <math.h>

namespace cg = cooperative_groups;

#define NT 8192
#define NO 8192
#define FIN 256
#define FOUT 64
#define SPLIT 4
#define JSP (NO/SPLIT)  // 2048 j per split
#define ROWT 64         // rows per attention tile-block (4 waves x 16 rows)
#define NBLK 512        // grid size everywhere (2 blocks/CU resident)

// workspace layout (float offsets)
#define OFF_ST  ((size_t)0)                           // 8192
#define OFF_SO  (OFF_ST + (size_t)NT)                 // 8192
#define OFF_WT  (OFF_SO + (size_t)NO)                 // 256
#define OFF_WO  (OFF_WT + (size_t)FIN)                // 256
#define OFF_NUM (OFF_WO + (size_t)FIN)                // SPLIT*NT*FOUT
#define OFF_DEN (OFF_NUM + (size_t)SPLIT*NT*FOUT)     // SPLIT*NT
#define OFF_HOB (OFF_DEN + (size_t)SPLIT*NT)          // NO*FOUT bf16 (B-frag order)
#define OFF_MSK (OFF_HOB + (size_t)NO*FOUT/2)         // NT*NO/32 u32, TRANSPOSED [jw][i]
// total ~= 4.7M floats ~= 19 MB of d_ws

typedef __attribute__((ext_vector_type(8))) short short8;
typedef __attribute__((ext_vector_type(4))) float float4v;

static __device__ __forceinline__ unsigned short f2bf(float x) {
  unsigned int u = __float_as_uint(x);
  unsigned int r = (u + 0x7fffu + ((u >> 16) & 1u)) >> 16;   // RNE
  return (unsigned short)r;
}
static __device__ __forceinline__ int pk2(float a, float b) {
  return (int)((unsigned int)f2bf(a) | ((unsigned int)f2bf(b) << 16));
}
static __device__ __forceinline__ float bflo(int p) {
  return __uint_as_float(((unsigned int)p) << 16);
}
static __device__ __forceinline__ float bfhi(int p) {
  return __uint_as_float(((unsigned int)p) & 0xffff0000u);
}

// ---------- phase bodies (shared by coop mega-kernel and fallback) ----------

// P1: wt = W_t @ a_t, wo = W_o @ a_o (one block's worth of work)
static __device__ __forceinline__ void phase1(const float* __restrict__ Wt,
                                              const float* __restrict__ Wo,
                                              const float* __restrict__ a,
                                              float* __restrict__ ws, int t) {
  float s1 = 0.f, s2 = 0.f;
#pragma unroll
  for (int fq = 0; fq < FOUT/4; ++fq) {
    float4 wt4 = *(const float4*)(Wt + (size_t)t*FOUT + fq*4);
    float4 wo4 = *(const float4*)(Wo + (size_t)t*FOUT + fq*4);
    float4 at4 = *(const float4*)(a + fq*4);
    float4 ao4 = *(const float4*)(a + FOUT + fq*4);
    s1 += wt4.x*at4.x + wt4.y*at4.y + wt4.z*at4.z + wt4.w*at4.w;
    s2 += wo4.x*ao4.x + wo4.y*ao4.y + wo4.z*ao4.z + wo4.w*ao4.w;
  }
  ws[OFF_WT + t] = s1;
  ws[OFF_WO + t] = s2;
}

// P2: s_t matvec (16 rows/block) + h_o GEMM -> hobp bf16 B-frag order + s_o
// (16 rows/block) + adj -> transposed bitmask [jw][i] (2048 waves x 128 words)
static __device__ __forceinline__ void phase2(const float* __restrict__ tin,
                                              const float* __restrict__ oin,
                                              const float* __restrict__ Wo,
                                              const float* __restrict__ a,
                                              const int* __restrict__ adj,
                                              float* __restrict__ ws,
                                              int b, int t) {
  int wv = t >> 6, lane = t & 63;
  // --- s_t: 4 rows/wave ---
  {
    float4 w = ((const float4*)(ws + OFF_WT))[lane];
#pragma unroll
    for (int r = 0; r < 4; ++r) {
      int row = b*16 + wv*4 + r;
      float4 v = ((const float4*)(tin + (size_t)row*FIN))[lane];
      float p = v.x*w.x + v.y*w.y + v.z*w.z + v.w*w.w;
#pragma unroll
      for (int m = 32; m >= 1; m >>= 1) p += __shfl_xor(p, m, 64);
      if (lane == 0) ws[OFF_ST + row] = p;
    }
  }
  // --- h_o: 4 rows/wave -> hobp (B-frag order) + s_o ---
  {
    unsigned short* hobp = (unsigned short*)(ws + OFF_HOB);
    int r0 = b*16 + wv*4;
    const float* ob = oin + (size_t)r0 * FIN;
    float acc[4];
#pragma unroll
    for (int r = 0; r < 4; ++r) acc[r] = 0.f;
#pragma unroll 2
    for (int k = 0; k < FIN; k += 4) {
      float w0 = Wo[(size_t)(k+0)*FOUT + lane];
      float w1 = Wo[(size_t)(k+1)*FOUT + lane];
      float w2 = Wo[(size_t)(k+2)*FOUT + lane];
      float w3 = Wo[(size_t)(k+3)*FOUT + lane];
#pragma unroll
      for (int r = 0; r < 4; ++r) {
        float4 ov = *(const float4*)(ob + (size_t)r*FIN + k);
        acc[r] = fmaf(ov.x, w0, acc[r]);
        acc[r] = fmaf(ov.y, w1, acc[r]);
        acc[r] = fmaf(ov.z, w2, acc[r]);
        acc[r] = fmaf(ov.w, w3, acc[r]);
      }
    }
    float ao = a[FOUT + lane];
    int fg = lane >> 4, n16 = lane & 15;
#pragma unroll
    for (int r = 0; r < 4; ++r) {
      int j = r0 + r;
      int jt = j >> 5, jl = j & 31;
      int ldst = (jl >> 3) * 16 + n16;       // consumer lane
      int e = jl & 7;
      hobp[(((size_t)jt*4 + fg)*64 + ldst)*8 + e] = f2bf(acc[r]);
      float p = acc[r] * ao;
#pragma unroll
      for (int m = 32; m >= 1; m >>= 1) p += __shfl_xor(p, m, 64);
      if (lane == 0) ws[OFF_SO + j] = p;
    }
  }
  // --- mask: adj -> transposed bitmask [jw][i] ---
  {
    unsigned int* mw = (unsigned int*)(ws + OFF_MSK);
    int g = b*4 + wv;                        // 2048 waves
    int i8 = g >> 1;                         // 8-row group 0..1023
    int jw0 = (g & 1) * 128;                 // 128 jw words per wave
    int rr = i8*8 + (lane >> 3);             // this lane's adj row
    int cc = (lane & 7) * 4;                 // col offset within word
    const int* ar = adj + (size_t)rr*NO + cc;
#pragma unroll 4
    for (int pp = 0; pp < 128; ++pp) {
      int jw = jw0 + pp;
      int4 a4 = *(const int4*)(ar + jw*32);
      unsigned int nib = (a4.x > 0 ? 1u : 0u) | (a4.y > 0 ? 2u : 0u)
                       | (a4.z > 0 ? 4u : 0u) | (a4.w > 0 ? 8u : 0u);
      unsigned int val = nib << ((lane & 7) * 4);
      val |= __shfl_xor((int)val, 1, 64);
      val |= __shfl_xor((int)val, 2, 64);
      val |= __shfl_xor((int)val, 4, 64);
      if ((lane & 7) == 0) mw[(size_t)jw*NT + i8*8 + (lane >> 3)] = val;
    }
  }
}

// P3: attention. Per wave: 16 rows x JSP j. A-frag in registers
// (expf + mask + bf16 pack + ds_bpermute), B from hobp, 4 MFMA/iter.
static __device__ __forceinline__ void phase3(float* __restrict__ ws, int b, int t) {
  const float* st = ws + OFF_ST;
  const float* so = ws + OFF_SO;
  const unsigned int* mT = (const unsigned int*)(ws + OFF_MSK);
  const unsigned short* hobp = (const unsigned short*)(ws + OFF_HOB);
  float* gnum = ws + OFF_NUM;
  float* gden = ws + OFF_DEN;

  int wv = t >> 6, lane = t & 63;
  int s  = b & (SPLIT - 1);
  int bi = b >> 2;                           // log2(SPLIT)
  int i0 = bi * ROWT;
  int jb = s * JSP;

  int rsrc = lane >> 2, csrc = lane & 3;     // source-lane map (coalesced)
  int irow_s = i0 + wv*16 + rsrc;
  float sti = st[irow_s];

  const unsigned int* mrow = mT + (size_t)(jb >> 5)*NT + irow_s;
  const float* sop = so + jb + csrc*8;
  const unsigned short* hpb = hobp + (size_t)(jb >> 5)*2048 + lane*8;

  int r16 = lane & 15, kg = lane >> 4;       // target A-frag map
  int sidx4 = ((r16 * 4 + kg) << 2);

  float4v acc0 = (float4v)0.f, acc1 = (float4v)0.f;
  float4v acc2 = (float4v)0.f, acc3 = (float4v)0.f;
  float dsum = 0.f;

#pragma unroll 1
  for (int tt = 0; tt < JSP/32; ++tt) {
    unsigned int mwv = mrow[(size_t)tt*NT];  // 64B/wave, coalesced
    float4 s0 = *(const float4*)(sop + tt*32);
    float4 s1 = *(const float4*)(sop + tt*32 + 4);
    const unsigned short* hb = hpb + (size_t)tt*2048;
    short8 b0 = *(const short8*)(hb);
    short8 b1 = *(const short8*)(hb + 512);
    short8 b2 = *(const short8*)(hb + 1024);
    short8 b3 = *(const short8*)(hb + 1536);

    unsigned int msh = mwv >> (csrc * 8);
    float x0 = sti + s0.x; x0 = fmaxf(x0, 0.2f*x0);
    float x1 = sti + s0.y; x1 = fmaxf(x1, 0.2f*x1);
    float x2 = sti + s0.z; x2 = fmaxf(x2, 0.2f*x2);
    float x3 = sti + s0.w; x3 = fmaxf(x3, 0.2f*x3);
    float x4 = sti + s1.x; x4 = fmaxf(x4, 0.2f*x4);
    float x5 = sti + s1.y; x5 = fmaxf(x5, 0.2f*x5);
    float x6 = sti + s1.z; x6 = fmaxf(x6, 0.2f*x6);
    float x7 = sti + s1.w; x7 = fmaxf(x7, 0.2f*x7);
    float w0 = (msh & 1u)   ? __expf(x0) : 0.f;
    float w1 = (msh & 2u)   ? __expf(x1) : 0.f;
    float w2 = (msh & 4u)   ? __expf(x2) : 0.f;
    float w3 = (msh & 8u)   ? __expf(x3) : 0.f;
    float w4 = (msh & 16u)  ? __expf(x4) : 0.f;
    float w5 = (msh & 32u)  ? __expf(x5) : 0.f;
    float w6 = (msh & 64u)  ? __expf(x6) : 0.f;
    float w7 = (msh & 128u) ? __expf(x7) : 0.f;

    int p0 = pk2(w0, w1);
    int p1 = pk2(w2, w3);
    int p2 = pk2(w4, w5);
    int p3 = pk2(w6, w7);
    dsum += bflo(p0) + bfhi(p0) + bflo(p1) + bfhi(p1)
          + bflo(p2) + bfhi(p2) + bflo(p3) + bfhi(p3);

    int4 ai;
    ai.x = __builtin_amdgcn_ds_bpermute(sidx4, p0);
    ai.y = __builtin_amdgcn_ds_bpermute(sidx4, p1);
    ai.z = __builtin_amdgcn_ds_bpermute(sidx4, p2);
    ai.w = __builtin_amdgcn_ds_bpermute(sidx4, p3);
    short8 afrag = *(short8*)&ai;

    acc0 = __builtin_amdgcn_mfma_f32_16x16x32_bf16(afrag, b0, acc0, 0, 0, 0);
    acc1 = __builtin_amdgcn_mfma_f32_16x16x32_bf16(afrag, b1, acc1, 0, 0, 0);
    acc2 = __builtin_amdgcn_mfma_f32_16x16x32_bf16(afrag, b2, acc2, 0, 0, 0);
    acc3 = __builtin_amdgcn_mfma_f32_16x16x32_bf16(afrag, b3, acc3, 0, 0, 0);
  }

  // den: reduce the 4 csrc-chunk partials per row
  dsum += __shfl_xor(dsum, 1, 64);
  dsum += __shfl_xor(dsum, 2, 64);
  if (csrc == 0) gden[(size_t)s*NT + i0 + wv*16 + rsrc] = dsum;

  // num: C/D layout col=lane&15, row=(lane>>4)*4+reg
  size_t obase = ((size_t)s*NT + i0 + wv*16 + kg*4) * FOUT + r16;
#pragma unroll
  for (int r = 0; r < 4; ++r) {
    gnum[obase + (size_t)r*FOUT +  0] = acc0[r];
    gnum[obase + (size_t)r*FOUT + 16] = acc1[r];
    gnum[obase + (size_t)r*FOUT + 32] = acc2[r];
    gnum[obase + (size_t)r*FOUT + 48] = acc3[r];
  }
}

// P4: combine splits, normalize, ELU
static __device__ __forceinline__ void phase4(const float* __restrict__ ws,
                                              float* __restrict__ out, int b, int t) {
#pragma unroll
  for (int q = 0; q < 4; ++q) {
    int idx = b*1024 + q*256 + t;            // 0..524287
    int i = idx >> 6;
    float num = 0.f, den = 0.f;
#pragma unroll
    for (int s = 0; s < SPLIT; ++s) {
      num += ws[OFF_NUM + ((size_t)s*NT + i)*FOUT + (idx & 63)];
      den += ws[OFF_DEN + (size_t)s*NT + i];
    }
    float r = num / den;
    out[idx] = (r > 0.f) ? r : (__expf(r) - 1.f);
  }
}

// ---------- cooperative mega-kernel (512 blocks = 2/CU, guaranteed) ----------
__launch_bounds__(256, 2)
__global__ void k_fused(const float* __restrict__ tin, const float* __restrict__ oin,
                        const float* __restrict__ Wt, const float* __restrict__ Wo,
                        const float* __restrict__ a, const int* __restrict__ adj,
                        float* __restrict__ ws, float* __restrict__ out) {
  cg::grid_group grid = cg::this_grid();
  int t = threadIdx.x, b = blockIdx.x;
  if (b == 0) phase1(Wt, Wo, a, ws, t);
  grid.sync();
  phase2(tin, oin, Wo, a, adj, ws, b, t);
  grid.sync();
  phase3(ws, b, t);
  grid.sync();
  phase4(ws, out, b, t);
}

// ---------- fallback: same phases as 4 regular kernels ----------
__launch_bounds__(256, 2)
__global__ void k_p1(const float* __restrict__ Wt, const float* __restrict__ Wo,
                     const float* __restrict__ a, float* __restrict__ ws) {
  phase1(Wt, Wo, a, ws, threadIdx.x);
}
__launch_bounds__(256, 2)
__global__ void k_p2(const float* __restrict__ tin, const float* __restrict__ oin,
                     const float* __restrict__ Wo, const float* __restrict__ a,
                     const int* __restrict__ adj, float* __restrict__ ws) {
  phase2(tin, oin, Wo, a, adj, ws, blockIdx.x, threadIdx.x);
}
__launch_bounds__(256, 2)
__global__ void k_p3(float* __restrict__ ws) {
  phase3(ws, blockIdx.x, threadIdx.x);
}
__launch_bounds__(256, 2)
__global__ void k_p4(const float* __restrict__ ws, float* __restrict__ out) {
  phase4(ws, out, blockIdx.x, threadIdx.x);
}

extern "C" void kernel_launch(void* const* d_in, const int* in_sizes, int n_in,
                              void* d_out, int out_size, void* d_ws, size_t ws_size,
                              hipStream_t stream) {
  const float* tin = (const float*)d_in[0];
  const float* oin = (const float*)d_in[1];
  const float* Wt  = (const float*)d_in[2];
  const float* Wo  = (const float*)d_in[3];
  const float* a   = (const float*)d_in[4];
  const int*   adj = (const int*)d_in[5];
  float* out = (float*)d_out;
  float* ws  = (float*)d_ws;

  // Capture-safe host-side residency check: no failed launches ever enqueued.
  int nb = 0;
  hipError_t qe = hipOccupancyMaxActiveBlocksPerMultiprocessor(
      &nb, (const void*)k_fused, 256, 0);
  bool coop_ok = (qe == hipSuccess) && (nb >= 2);

  if (coop_ok) {
    void* args[] = {(void*)&tin, (void*)&oin, (void*)&Wt, (void*)&Wo,
                    (void*)&a, (void*)&adj, (void*)&ws, (void*)&out};
    hipError_t le = hipLaunchCooperativeKernel((const void*)k_fused,
                                               dim3(NBLK), dim3(256),
                                               args, 0, stream);
    if (le == hipSuccess) return;
  }
  // Fallback: identical phases as regular kernels.
  hipLaunchKernelGGL(k_p1, dim3(1),    dim3(256), 0, stream, Wt, Wo, a, ws);
  hipLaunchKernelGGL(k_p2, dim3(NBLK), dim3(256), 0, stream, tin, oin, Wo, a, adj, ws);
  hipLaunchKernelGGL(k_p3, dim3(NBLK), dim3(256), 0, stream, ws);
  hipLaunchKernelGGL(k_p4, dim3(NBLK), dim3(256), 0, stream, ws, out);
}

// Round 8
// 502.223 us; speedup vs baseline: 1.3089x; 1.3089x over previous
//
#include <hip/hip_runtime.h>
#include <math.h>

#define NT 8192
#define NO 8192
#define FIN 256
#define FOUT 64
#define SPLIT 8
#define JSP (NO/SPLIT)  // 1024 j per split
#define ROWT 64         // rows per attention block (4 waves x 16 rows)

// workspace layout (float offsets)
#define OFF_ST  ((size_t)0)                           // 8192
#define OFF_SO  (OFF_ST + (size_t)NT)                 // 8192
#define OFF_WT  (OFF_SO + (size_t)NO)                 // 256
#define OFF_WO  (OFF_WT + (size_t)FIN)                // 256
#define OFF_NUM (OFF_WO + (size_t)FIN)                // SPLIT*NT*FOUT
#define OFF_DEN (OFF_NUM + (size_t)SPLIT*NT*FOUT)     // SPLIT*NT
#define OFF_HOB (OFF_DEN + (size_t)SPLIT*NT)          // NO*FOUT bf16 (B-frag order)
#define OFF_MSK (OFF_HOB + (size_t)NO*FOUT/2)         // NT*NO/32 u32, TRANSPOSED [jw][i]
// total ~= 6.8M floats ~= 27 MB of d_ws

typedef __attribute__((ext_vector_type(8))) short short8;
typedef __attribute__((ext_vector_type(4))) float float4v;

static __device__ __forceinline__ unsigned short f2bf(float x) {
  unsigned int u = __float_as_uint(x);
  unsigned int r = (u + 0x7fffu + ((u >> 16) & 1u)) >> 16;   // RNE
  return (unsigned short)r;
}
static __device__ __forceinline__ int pk2(float a, float b) {
  return (int)((unsigned int)f2bf(a) | ((unsigned int)f2bf(b) << 16));
}
static __device__ __forceinline__ float bflo(int p) {
  return __uint_as_float(((unsigned int)p) << 16);
}
static __device__ __forceinline__ float bfhi(int p) {
  return __uint_as_float(((unsigned int)p) & 0xffff0000u);
}

// K1: fold wt = W_t @ a_t, wo = W_o @ a_o
__global__ void k_wvec(const float* __restrict__ Wt, const float* __restrict__ Wo,
                       const float* __restrict__ a, float* __restrict__ ws) {
  int t = threadIdx.x;
  float s1 = 0.f, s2 = 0.f;
#pragma unroll
  for (int fq = 0; fq < FOUT/4; ++fq) {
    float4 wt4 = *(const float4*)(Wt + (size_t)t*FOUT + fq*4);
    float4 wo4 = *(const float4*)(Wo + (size_t)t*FOUT + fq*4);
    float4 at4 = *(const float4*)(a + fq*4);
    float4 ao4 = *(const float4*)(a + FOUT + fq*4);
    s1 += wt4.x*at4.x + wt4.y*at4.y + wt4.z*at4.z + wt4.w*at4.w;
    s2 += wo4.x*ao4.x + wo4.y*ao4.y + wo4.z*ao4.z + wo4.w*ao4.w;
  }
  ws[OFF_WT + t] = s1;
  ws[OFF_WO + t] = s2;
}

// K2: s_t matvec (16 rows/block) + h_o GEMM -> hobp bf16 B-frag order + s_o.
// (R7 phase2 minus the mask part; verified correct end-to-end.)
__global__ void k_prep(const float* __restrict__ tin, const float* __restrict__ oin,
                       const float* __restrict__ Wo, const float* __restrict__ a,
                       float* __restrict__ ws) {
  int b = blockIdx.x, t = threadIdx.x;
  int wv = t >> 6, lane = t & 63;
  // --- s_t: 4 rows/wave ---
  {
    float4 w = ((const float4*)(ws + OFF_WT))[lane];
#pragma unroll
    for (int r = 0; r < 4; ++r) {
      int row = b*16 + wv*4 + r;
      float4 v = ((const float4*)(tin + (size_t)row*FIN))[lane];
      float p = v.x*w.x + v.y*w.y + v.z*w.z + v.w*w.w;
#pragma unroll
      for (int m = 32; m >= 1; m >>= 1) p += __shfl_xor(p, m, 64);
      if (lane == 0) ws[OFF_ST + row] = p;
    }
  }
  // --- h_o: 4 rows/wave -> hobp (B-frag order) + s_o ---
  {
    unsigned short* hobp = (unsigned short*)(ws + OFF_HOB);
    int r0 = b*16 + wv*4;
    const float* ob = oin + (size_t)r0 * FIN;
    float acc[4];
#pragma unroll
    for (int r = 0; r < 4; ++r) acc[r] = 0.f;
#pragma unroll 2
    for (int k = 0; k < FIN; k += 4) {
      float w0 = Wo[(size_t)(k+0)*FOUT + lane];
      float w1 = Wo[(size_t)(k+1)*FOUT + lane];
      float w2 = Wo[(size_t)(k+2)*FOUT + lane];
      float w3 = Wo[(size_t)(k+3)*FOUT + lane];
#pragma unroll
      for (int r = 0; r < 4; ++r) {
        float4 ov = *(const float4*)(ob + (size_t)r*FIN + k);
        acc[r] = fmaf(ov.x, w0, acc[r]);
        acc[r] = fmaf(ov.y, w1, acc[r]);
        acc[r] = fmaf(ov.z, w2, acc[r]);
        acc[r] = fmaf(ov.w, w3, acc[r]);
      }
    }
    float ao = a[FOUT + lane];
    int fg = lane >> 4, n16 = lane & 15;
#pragma unroll
    for (int r = 0; r < 4; ++r) {
      int j = r0 + r;
      int jt = j >> 5, jl = j & 31;
      int ldst = (jl >> 3) * 16 + n16;       // consumer lane
      int e = jl & 7;
      hobp[(((size_t)jt*4 + fg)*64 + ldst)*8 + e] = f2bf(acc[r]);
      float p = acc[r] * ao;
#pragma unroll
      for (int m = 32; m >= 1; m >>= 1) p += __shfl_xor(p, m, 64);
      if (lane == 0) ws[OFF_SO + j] = p;
    }
  }
}

// K3: adj -> transposed bitmask [jw][i] via __ballot. One wave per adj row:
// perfectly sequential 256B reads (128 iters), 1 cmp + 1 ballot per 64 j,
// two 4B stores (write side is only 8.4 MB; L2/L3 absorbs).
__global__ void k_mask(const int* __restrict__ adj, float* __restrict__ ws) {
  unsigned int* mw = (unsigned int*)(ws + OFF_MSK);
  int wv = threadIdx.x >> 6, lane = threadIdx.x & 63;
  int i = blockIdx.x * 4 + wv;               // one row per wave (8192 waves)
  const int* ar = adj + (size_t)i*NO;
#pragma unroll 4
  for (int jg = 0; jg < NO/64; ++jg) {       // 128 iters of 64 j
    int v = ar[jg*64 + lane];
    unsigned long long m = __ballot(v > 0);
    if (lane == 0) {
      mw[(size_t)(2*jg)  *NT + i] = (unsigned int)m;
      mw[(size_t)(2*jg+1)*NT + i] = (unsigned int)(m >> 32);
    }
  }
}

// K4: attention (R7 phase3, verified). Per wave: 16 rows x 1024 j, 32 iters.
// A-frag in registers (expf + mask + bf16 pack + ds_bpermute), B from hobp
// (coalesced B-frag order), mask read is one 64B segment per wave-iter.
__launch_bounds__(256, 4)
__global__ void k_attn(float* __restrict__ ws) {
  const float* st = ws + OFF_ST;
  const float* so = ws + OFF_SO;
  const unsigned int* mT = (const unsigned int*)(ws + OFF_MSK);
  const unsigned short* hobp = (const unsigned short*)(ws + OFF_HOB);
  float* gnum = ws + OFF_NUM;
  float* gden = ws + OFF_DEN;

  int t = threadIdx.x, b = blockIdx.x;
  int wv = t >> 6, lane = t & 63;
  int s  = b & (SPLIT - 1);
  int bi = b >> 3;                           // log2(SPLIT)
  int i0 = bi * ROWT;
  int jb = s * JSP;

  int rsrc = lane >> 2, csrc = lane & 3;     // source-lane map (coalesced)
  int irow_s = i0 + wv*16 + rsrc;
  float sti = st[irow_s];

  const unsigned int* mrow = mT + (size_t)(jb >> 5)*NT + irow_s;
  const float* sop = so + jb + csrc*8;
  const unsigned short* hpb = hobp + (size_t)(jb >> 5)*2048 + lane*8;

  int r16 = lane & 15, kg = lane >> 4;       // target A-frag map
  int sidx4 = ((r16 * 4 + kg) << 2);

  float4v acc0 = (float4v)0.f, acc1 = (float4v)0.f;
  float4v acc2 = (float4v)0.f, acc3 = (float4v)0.f;
  float dsum = 0.f;

#pragma unroll 2
  for (int tt = 0; tt < JSP/32; ++tt) {
    unsigned int mwv = mrow[(size_t)tt*NT];  // 64B/wave, coalesced
    float4 s0 = *(const float4*)(sop + tt*32);
    float4 s1 = *(const float4*)(sop + tt*32 + 4);
    const unsigned short* hb = hpb + (size_t)tt*2048;
    short8 b0 = *(const short8*)(hb);
    short8 b1 = *(const short8*)(hb + 512);
    short8 b2 = *(const short8*)(hb + 1024);
    short8 b3 = *(const short8*)(hb + 1536);

    unsigned int msh = mwv >> (csrc * 8);
    float x0 = sti + s0.x; x0 = fmaxf(x0, 0.2f*x0);
    float x1 = sti + s0.y; x1 = fmaxf(x1, 0.2f*x1);
    float x2 = sti + s0.z; x2 = fmaxf(x2, 0.2f*x2);
    float x3 = sti + s0.w; x3 = fmaxf(x3, 0.2f*x3);
    float x4 = sti + s1.x; x4 = fmaxf(x4, 0.2f*x4);
    float x5 = sti + s1.y; x5 = fmaxf(x5, 0.2f*x5);
    float x6 = sti + s1.z; x6 = fmaxf(x6, 0.2f*x6);
    float x7 = sti + s1.w; x7 = fmaxf(x7, 0.2f*x7);
    float w0 = (msh & 1u)   ? __expf(x0) : 0.f;
    float w1 = (msh & 2u)   ? __expf(x1) : 0.f;
    float w2 = (msh & 4u)   ? __expf(x2) : 0.f;
    float w3 = (msh & 8u)   ? __expf(x3) : 0.f;
    float w4 = (msh & 16u)  ? __expf(x4) : 0.f;
    float w5 = (msh & 32u)  ? __expf(x5) : 0.f;
    float w6 = (msh & 64u)  ? __expf(x6) : 0.f;
    float w7 = (msh & 128u) ? __expf(x7) : 0.f;

    int p0 = pk2(w0, w1);
    int p1 = pk2(w2, w3);
    int p2 = pk2(w4, w5);
    int p3 = pk2(w6, w7);
    dsum += bflo(p0) + bfhi(p0) + bflo(p1) + bfhi(p1)
          + bflo(p2) + bfhi(p2) + bflo(p3) + bfhi(p3);

    int4 ai;
    ai.x = __builtin_amdgcn_ds_bpermute(sidx4, p0);
    ai.y = __builtin_amdgcn_ds_bpermute(sidx4, p1);
    ai.z = __builtin_amdgcn_ds_bpermute(sidx4, p2);
    ai.w = __builtin_amdgcn_ds_bpermute(sidx4, p3);
    short8 afrag = *(short8*)&ai;

    acc0 = __builtin_amdgcn_mfma_f32_16x16x32_bf16(afrag, b0, acc0, 0, 0, 0);
    acc1 = __builtin_amdgcn_mfma_f32_16x16x32_bf16(afrag, b1, acc1, 0, 0, 0);
    acc2 = __builtin_amdgcn_mfma_f32_16x16x32_bf16(afrag, b2, acc2, 0, 0, 0);
    acc3 = __builtin_amdgcn_mfma_f32_16x16x32_bf16(afrag, b3, acc3, 0, 0, 0);
  }

  // den: reduce the 4 csrc-chunk partials per row
  dsum += __shfl_xor(dsum, 1, 64);
  dsum += __shfl_xor(dsum, 2, 64);
  if (csrc == 0) gden[(size_t)s*NT + i0 + wv*16 + rsrc] = dsum;

  // num: C/D layout col=lane&15, row=(lane>>4)*4+reg
  size_t obase = ((size_t)s*NT + i0 + wv*16 + kg*4) * FOUT + r16;
#pragma unroll
  for (int r = 0; r < 4; ++r) {
    gnum[obase + (size_t)r*FOUT +  0] = acc0[r];
    gnum[obase + (size_t)r*FOUT + 16] = acc1[r];
    gnum[obase + (size_t)r*FOUT + 32] = acc2[r];
    gnum[obase + (size_t)r*FOUT + 48] = acc3[r];
  }
}

// K5: combine splits, normalize, ELU
__global__ void k_comb(const float* __restrict__ ws, float* __restrict__ out) {
  int idx = blockIdx.x * 256 + threadIdx.x;   // 0..524287
  int i = idx >> 6;
  float num = 0.f, den = 0.f;
#pragma unroll
  for (int s = 0; s < SPLIT; ++s) {
    num += ws[OFF_NUM + ((size_t)s*NT + i)*FOUT + (idx & 63)];
    den += ws[OFF_DEN + (size_t)s*NT + i];
  }
  float r = num / den;
  out[idx] = (r > 0.f) ? r : (__expf(r) - 1.f);
}

extern "C" void kernel_launch(void* const* d_in, const int* in_sizes, int n_in,
                              void* d_out, int out_size, void* d_ws, size_t ws_size,
                              hipStream_t stream) {
  const float* tin = (const float*)d_in[0];
  const float* oin = (const float*)d_in[1];
  const float* Wt  = (const float*)d_in[2];
  const float* Wo  = (const float*)d_in[3];
  const float* a   = (const float*)d_in[4];
  const int*   adj = (const int*)d_in[5];
  float* out = (float*)d_out;
  float* ws  = (float*)d_ws;

  hipLaunchKernelGGL(k_wvec, dim3(1),              dim3(256), 0, stream, Wt, Wo, a, ws);
  hipLaunchKernelGGL(k_mask, dim3(NT/4),           dim3(256), 0, stream, adj, ws);
  hipLaunchKernelGGL(k_prep, dim3(NT/16),          dim3(256), 0, stream, tin, oin, Wo, a, ws);
  hipLaunchKernelGGL(k_attn, dim3(NT/ROWT*SPLIT),  dim3(256), 0, stream, ws);
  hipLaunchKernelGGL(k_comb, dim3(NT*FOUT/256),    dim3(256), 0, stream, ws, out);
}

// Round 9
// 473.734 us; speedup vs baseline: 1.3876x; 1.0601x over previous
//
#include <hip/hip_runtime.h>
#include <math.h>

#define NT 8192
#define NO 8192
#define FIN 256
#define FOUT 64
#define SPLIT 8
#define JSP (NO/SPLIT)  // 1024 j per split
#define ROWT 64         // rows per attention block (4 waves x 16 rows)

// workspace layout (float offsets)
#define OFF_ST  ((size_t)0)                           // 8192
#define OFF_SO  (OFF_ST + (size_t)NT)                 // 8192
#define OFF_WT  (OFF_SO + (size_t)NO)                 // 256
#define OFF_WO  (OFF_WT + (size_t)FIN)                // 256
#define OFF_NUM (OFF_WO + (size_t)FIN)                // SPLIT*NT*FOUT
#define OFF_DEN (OFF_NUM + (size_t)SPLIT*NT*FOUT)     // SPLIT*NT
#define OFF_HOB (OFF_DEN + (size_t)SPLIT*NT)          // NO*FOUT bf16 (B-frag order)
#define OFF_MSK (OFF_HOB + (size_t)NO*FOUT/2)         // NT*NO/32 u32, TRANSPOSED [jw][i]
// total ~= 6.8M floats ~= 27 MB of d_ws

typedef __attribute__((ext_vector_type(8))) short short8;
typedef __attribute__((ext_vector_type(4))) float float4v;

static __device__ __forceinline__ unsigned short f2bf(float x) {
  unsigned int u = __float_as_uint(x);
  unsigned int r = (u + 0x7fffu + ((u >> 16) & 1u)) >> 16;   // RNE
  return (unsigned short)r;
}
static __device__ __forceinline__ int pk2(float a, float b) {
  return (int)((unsigned int)f2bf(a) | ((unsigned int)f2bf(b) << 16));
}
static __device__ __forceinline__ float bflo(int p) {
  return __uint_as_float(((unsigned int)p) << 16);
}
static __device__ __forceinline__ float bfhi(int p) {
  return __uint_as_float(((unsigned int)p) & 0xffff0000u);
}

// K1: fold wt = W_t @ a_t, wo = W_o @ a_o
__global__ void k_wvec(const float* __restrict__ Wt, const float* __restrict__ Wo,
                       const float* __restrict__ a, float* __restrict__ ws) {
  int t = threadIdx.x;
  float s1 = 0.f, s2 = 0.f;
#pragma unroll
  for (int fq = 0; fq < FOUT/4; ++fq) {
    float4 wt4 = *(const float4*)(Wt + (size_t)t*FOUT + fq*4);
    float4 wo4 = *(const float4*)(Wo + (size_t)t*FOUT + fq*4);
    float4 at4 = *(const float4*)(a + fq*4);
    float4 ao4 = *(const float4*)(a + FOUT + fq*4);
    s1 += wt4.x*at4.x + wt4.y*at4.y + wt4.z*at4.z + wt4.w*at4.w;
    s2 += wo4.x*ao4.x + wo4.y*ao4.y + wo4.z*ao4.z + wo4.w*ao4.w;
  }
  ws[OFF_WT + t] = s1;
  ws[OFF_WO + t] = s2;
}

// K2: s_t matvec + h_o GEMM -> hobp bf16 B-frag order + s_o. (verified)
__global__ void k_prep(const float* __restrict__ tin, const float* __restrict__ oin,
                       const float* __restrict__ Wo, const float* __restrict__ a,
                       float* __restrict__ ws) {
  int b = blockIdx.x, t = threadIdx.x;
  int wv = t >> 6, lane = t & 63;
  // --- s_t: 4 rows/wave ---
  {
    float4 w = ((const float4*)(ws + OFF_WT))[lane];
#pragma unroll
    for (int r = 0; r < 4; ++r) {
      int row = b*16 + wv*4 + r;
      float4 v = ((const float4*)(tin + (size_t)row*FIN))[lane];
      float p = v.x*w.x + v.y*w.y + v.z*w.z + v.w*w.w;
#pragma unroll
      for (int m = 32; m >= 1; m >>= 1) p += __shfl_xor(p, m, 64);
      if (lane == 0) ws[OFF_ST + row] = p;
    }
  }
  // --- h_o: 4 rows/wave -> hobp (B-frag order) + s_o ---
  {
    unsigned short* hobp = (unsigned short*)(ws + OFF_HOB);
    int r0 = b*16 + wv*4;
    const float* ob = oin + (size_t)r0 * FIN;
    float acc[4];
#pragma unroll
    for (int r = 0; r < 4; ++r) acc[r] = 0.f;
#pragma unroll 2
    for (int k = 0; k < FIN; k += 4) {
      float w0 = Wo[(size_t)(k+0)*FOUT + lane];
      float w1 = Wo[(size_t)(k+1)*FOUT + lane];
      float w2 = Wo[(size_t)(k+2)*FOUT + lane];
      float w3 = Wo[(size_t)(k+3)*FOUT + lane];
#pragma unroll
      for (int r = 0; r < 4; ++r) {
        float4 ov = *(const float4*)(ob + (size_t)r*FIN + k);
        acc[r] = fmaf(ov.x, w0, acc[r]);
        acc[r] = fmaf(ov.y, w1, acc[r]);
        acc[r] = fmaf(ov.z, w2, acc[r]);
        acc[r] = fmaf(ov.w, w3, acc[r]);
      }
    }
    float ao = a[FOUT + lane];
    int fg = lane >> 4, n16 = lane & 15;
#pragma unroll
    for (int r = 0; r < 4; ++r) {
      int j = r0 + r;
      int jt = j >> 5, jl = j & 31;
      int ldst = (jl >> 3) * 16 + n16;       // consumer lane
      int e = jl & 7;
      hobp[(((size_t)jt*4 + fg)*64 + ldst)*8 + e] = f2bf(acc[r]);
      float p = acc[r] * ao;
#pragma unroll
      for (int m = 32; m >= 1; m >>= 1) p += __shfl_xor(p, m, 64);
      if (lane == 0) ws[OFF_SO + j] = p;
    }
  }
}

// K3: adj -> transposed bitmask [jw][i], BOTH sides coalesced.
// Block = 64 rows x 1024 j (1024 blocks, 4/CU). Reads: int4 = 1KB/wave-instr
// sequential. Pack: 3 shfl-ors -> full 32-bit word in each 8-lane group.
// Stage in padded LDS (stride 65 -> conflict-free writes AND reads), then
// store phase writes 64 consecutive i per jw = 256B coalesced per instr.
__global__ void k_mask(const int* __restrict__ adj, float* __restrict__ ws) {
  __shared__ unsigned int lds[32*65];        // 8.3 KB
  unsigned int* mw = (unsigned int*)(ws + OFF_MSK);
  int t = threadIdx.x, b = blockIdx.x;
  int wv = t >> 6, lane = t & 63;
  int ib = b >> 3, jblk = b & 7;
  int i0 = ib * 64;
  const int* base = adj + (size_t)(i0 + wv*16)*NO + jblk*1024 + lane*4;
#pragma unroll 2
  for (int rr = 0; rr < 16; ++rr) {
    const int* ar = base + (size_t)rr*NO;
#pragma unroll
    for (int q = 0; q < 4; ++q) {
      int4 a4 = *(const int4*)(ar + q*256);
      unsigned int nib = (a4.x > 0 ? 1u : 0u) | (a4.y > 0 ? 2u : 0u)
                       | (a4.z > 0 ? 4u : 0u) | (a4.w > 0 ? 8u : 0u);
      unsigned int val = nib << ((lane & 7) * 4);
      val |= __shfl_xor((int)val, 1, 64);
      val |= __shfl_xor((int)val, 2, 64);
      val |= __shfl_xor((int)val, 4, 64);
      if ((lane & 7) == 0)
        lds[(q*8 + (lane >> 3))*65 + wv*16 + rr] = val;
    }
  }
  __syncthreads();
  int jwb = jblk * 32;
#pragma unroll
  for (int p = 0; p < 8; ++p) {
    int w = wv*8 + p;
    mw[(size_t)(jwb + w)*NT + i0 + lane] = lds[w*65 + lane];
  }
}

// K4: attention (verified R7/R8). Per wave: 16 rows x 1024 j, 32 iters.
// A-frag in registers (expf + mask + bf16 pack + ds_bpermute), B from hobp
// (coalesced B-frag order), mask read = one 64B segment per wave-iter.
__launch_bounds__(256, 4)
__global__ void k_attn(float* __restrict__ ws) {
  const float* st = ws + OFF_ST;
  const float* so = ws + OFF_SO;
  const unsigned int* mT = (const unsigned int*)(ws + OFF_MSK);
  const unsigned short* hobp = (const unsigned short*)(ws + OFF_HOB);
  float* gnum = ws + OFF_NUM;
  float* gden = ws + OFF_DEN;

  int t = threadIdx.x, b = blockIdx.x;
  int wv = t >> 6, lane = t & 63;
  int s  = b & (SPLIT - 1);
  int bi = b >> 3;                           // log2(SPLIT)
  int i0 = bi * ROWT;
  int jb = s * JSP;

  int rsrc = lane >> 2, csrc = lane & 3;     // source-lane map (coalesced)
  int irow_s = i0 + wv*16 + rsrc;
  float sti = st[irow_s];

  const unsigned int* mrow = mT + (size_t)(jb >> 5)*NT + irow_s;
  const float* sop = so + jb + csrc*8;
  const unsigned short* hpb = hobp + (size_t)(jb >> 5)*2048 + lane*8;

  int r16 = lane & 15, kg = lane >> 4;       // target A-frag map
  int sidx4 = ((r16 * 4 + kg) << 2);

  float4v acc0 = (float4v)0.f, acc1 = (float4v)0.f;
  float4v acc2 = (float4v)0.f, acc3 = (float4v)0.f;
  float dsum = 0.f;

#pragma unroll 2
  for (int tt = 0; tt < JSP/32; ++tt) {
    unsigned int mwv = mrow[(size_t)tt*NT];  // 64B/wave, coalesced
    float4 s0 = *(const float4*)(sop + tt*32);
    float4 s1 = *(const float4*)(sop + tt*32 + 4);
    const unsigned short* hb = hpb + (size_t)tt*2048;
    short8 b0 = *(const short8*)(hb);
    short8 b1 = *(const short8*)(hb + 512);
    short8 b2 = *(const short8*)(hb + 1024);
    short8 b3 = *(const short8*)(hb + 1536);

    unsigned int msh = mwv >> (csrc * 8);
    float x0 = sti + s0.x; x0 = fmaxf(x0, 0.2f*x0);
    float x1 = sti + s0.y; x1 = fmaxf(x1, 0.2f*x1);
    float x2 = sti + s0.z; x2 = fmaxf(x2, 0.2f*x2);
    float x3 = sti + s0.w; x3 = fmaxf(x3, 0.2f*x3);
    float x4 = sti + s1.x; x4 = fmaxf(x4, 0.2f*x4);
    float x5 = sti + s1.y; x5 = fmaxf(x5, 0.2f*x5);
    float x6 = sti + s1.z; x6 = fmaxf(x6, 0.2f*x6);
    float x7 = sti + s1.w; x7 = fmaxf(x7, 0.2f*x7);
    float w0 = (msh & 1u)   ? __expf(x0) : 0.f;
    float w1 = (msh & 2u)   ? __expf(x1) : 0.f;
    float w2 = (msh & 4u)   ? __expf(x2) : 0.f;
    float w3 = (msh & 8u)   ? __expf(x3) : 0.f;
    float w4 = (msh & 16u)  ? __expf(x4) : 0.f;
    float w5 = (msh & 32u)  ? __expf(x5) : 0.f;
    float w6 = (msh & 64u)  ? __expf(x6) : 0.f;
    float w7 = (msh & 128u) ? __expf(x7) : 0.f;

    int p0 = pk2(w0, w1);
    int p1 = pk2(w2, w3);
    int p2 = pk2(w4, w5);
    int p3 = pk2(w6, w7);
    dsum += bflo(p0) + bfhi(p0) + bflo(p1) + bfhi(p1)
          + bflo(p2) + bfhi(p2) + bflo(p3) + bfhi(p3);

    int4 ai;
    ai.x = __builtin_amdgcn_ds_bpermute(sidx4, p0);
    ai.y = __builtin_amdgcn_ds_bpermute(sidx4, p1);
    ai.z = __builtin_amdgcn_ds_bpermute(sidx4, p2);
    ai.w = __builtin_amdgcn_ds_bpermute(sidx4, p3);
    short8 afrag = *(short8*)&ai;

    acc0 = __builtin_amdgcn_mfma_f32_16x16x32_bf16(afrag, b0, acc0, 0, 0, 0);
    acc1 = __builtin_amdgcn_mfma_f32_16x16x32_bf16(afrag, b1, acc1, 0, 0, 0);
    acc2 = __builtin_amdgcn_mfma_f32_16x16x32_bf16(afrag, b2, acc2, 0, 0, 0);
    acc3 = __builtin_amdgcn_mfma_f32_16x16x32_bf16(afrag, b3, acc3, 0, 0, 0);
  }

  // den: reduce the 4 csrc-chunk partials per row
  dsum += __shfl_xor(dsum, 1, 64);
  dsum += __shfl_xor(dsum, 2, 64);
  if (csrc == 0) gden[(size_t)s*NT + i0 + wv*16 + rsrc] = dsum;

  // num: C/D layout col=lane&15, row=(lane>>4)*4+reg
  size_t obase = ((size_t)s*NT + i0 + wv*16 + kg*4) * FOUT + r16;
#pragma unroll
  for (int r = 0; r < 4; ++r) {
    gnum[obase + (size_t)r*FOUT +  0] = acc0[r];
    gnum[obase + (size_t)r*FOUT + 16] = acc1[r];
    gnum[obase + (size_t)r*FOUT + 32] = acc2[r];
    gnum[obase + (size_t)r*FOUT + 48] = acc3[r];
  }
}

// K5: combine splits, normalize, ELU
__global__ void k_comb(const float* __restrict__ ws, float* __restrict__ out) {
  int idx = blockIdx.x * 256 + threadIdx.x;   // 0..524287
  int i = idx >> 6;
  float num = 0.f, den = 0.f;
#pragma unroll
  for (int s = 0; s < SPLIT; ++s) {
    num += ws[OFF_NUM + ((size_t)s*NT + i)*FOUT + (idx & 63)];
    den += ws[OFF_DEN + (size_t)s*NT + i];
  }
  float r = num / den;
  out[idx] = (r > 0.f) ? r : (__expf(r) - 1.f);
}

extern "C" void kernel_launch(void* const* d_in, const int* in_sizes, int n_in,
                              void* d_out, int out_size, void* d_ws, size_t ws_size,
                              hipStream_t stream) {
  const float* tin = (const float*)d_in[0];
  const float* oin = (const float*)d_in[1];
  const float* Wt  = (const float*)d_in[2];
  const float* Wo  = (const float*)d_in[3];
  const float* a   = (const float*)d_in[4];
  const int*   adj = (const int*)d_in[5];
  float* out = (float*)d_out;
  float* ws  = (float*)d_ws;

  hipLaunchKernelGGL(k_wvec, dim3(1),              dim3(256), 0, stream, Wt, Wo, a, ws);
  hipLaunchKernelGGL(k_mask, dim3(1024),           dim3(256), 0, stream, adj, ws);
  hipLaunchKernelGGL(k_prep, dim3(NT/16),          dim3(256), 0, stream, tin, oin, Wo, a, ws);
  hipLaunchKernelGGL(k_attn, dim3(NT/ROWT*SPLIT),  dim3(256), 0, stream, ws);
  hipLaunchKernelGGL(k_comb, dim3(NT*FOUT/256),    dim3(256), 0, stream, ws, out);
}